// Round 2
// baseline (510.058 us; speedup 1.0000x reference)
//
#include <hip/hip_runtime.h>
#include <hip/hip_bf16.h>

// MHA: B=4, S=2048, D=1024, H=16, DH=64.  All matmuls via mfma_f32_16x16x32_bf16.
// ws layout (bytes): WTq@0 WTk@2M WTv@4M WTo@6M  Q@8M K@24M VT@40M Xattn@56M (end 72M)

typedef __bf16 bf16x8 __attribute__((ext_vector_type(8)));
typedef float f32x4 __attribute__((ext_vector_type(4)));

static __device__ __forceinline__ unsigned short f2bf(float f) {
    __bf16 h = (__bf16)f;                       // RNE
    return __builtin_bit_cast(unsigned short, h);
}

// ---------------- weight transpose: W fp32 [K=1024][N=1024] -> W^T bf16 [N][K]
__global__ void transpose_weights(const float* __restrict__ W0, const float* __restrict__ W1,
                                  const float* __restrict__ W2, const float* __restrict__ W3,
                                  unsigned short* __restrict__ T0, unsigned short* __restrict__ T1,
                                  unsigned short* __restrict__ T2, unsigned short* __restrict__ T3) {
    const float* W; unsigned short* T;
    switch (blockIdx.z) { case 0: W=W0; T=T0; break; case 1: W=W1; T=T1; break;
                          case 2: W=W2; T=T2; break; default: W=W3; T=T3; }
    __shared__ float tile[32][33];
    int tx = threadIdx.x, ty = threadIdx.y;
    int k0 = blockIdx.x * 32, n0 = blockIdx.y * 32;
#pragma unroll
    for (int j = 0; j < 4; j++) tile[ty + 8*j][tx] = W[(size_t)(k0 + ty + 8*j) * 1024 + n0 + tx];
    __syncthreads();
#pragma unroll
    for (int j = 0; j < 4; j++) T[(size_t)(n0 + ty + 8*j) * 1024 + k0 + tx] = f2bf(tile[tx][ty + 8*j]);
}

// ---------------- GEMM: C[M=8192][N=1024] = A[M][K=1024] * W + bias, B given as W^T bf16 [N][K]
// MODE 0: out=Q bf16 [B,H,S,DH], scaled by 0.125   MODE 1: out=K bf16 [B,H,S,DH]
// MODE 2: out=V^T bf16 [B,H,DH,S]                  MODE 3: out=fp32 [M][N] (d_out)
template <bool ABF16, int MODE>
__global__ __launch_bounds__(256) void gemm_bt(const void* __restrict__ Av,
                                               const unsigned short* __restrict__ BT,
                                               const float* __restrict__ bias,
                                               void* __restrict__ Out) {
    __shared__ uint4 Asm[128 * 8];   // 128 rows x 64 k bf16, 8 slots of 16B, XOR-swizzled
    __shared__ uint4 Bsm[128 * 8];
    const int t = threadIdx.x;
    const int lane = t & 63, w = t >> 6;
    const int g = lane >> 4, r16 = lane & 15;
    const int wr = w >> 1, wc = w & 1;
    const int rowBase = blockIdx.y * 128, colBase = blockIdx.x * 128;
    const int K = 1024;
    const int srow = t >> 1, shalf = t & 1;   // staging: thread owns row srow, 32 elems

    f32x4 acc[4][4] = {};

    for (int k0 = 0; k0 < K; k0 += 64) {
        __syncthreads();
        if (ABF16) {
            const unsigned short* A = (const unsigned short*)Av;
            const uint4* src = (const uint4*)(A + (size_t)(rowBase + srow) * K + k0 + 32 * shalf);
#pragma unroll
            for (int j = 0; j < 4; j++) {
                int slot = 4 * shalf + j;
                Asm[srow * 8 + (slot ^ (srow & 7))] = src[j];
            }
        } else {
            const float* A = (const float*)Av;
            const float4* src = (const float4*)(A + (size_t)(rowBase + srow) * K + k0 + 32 * shalf);
            unsigned short h[32];
#pragma unroll
            for (int j = 0; j < 8; j++) {
                float4 v = src[j];
                h[4*j+0] = f2bf(v.x); h[4*j+1] = f2bf(v.y); h[4*j+2] = f2bf(v.z); h[4*j+3] = f2bf(v.w);
            }
#pragma unroll
            for (int j = 0; j < 4; j++) {
                int slot = 4 * shalf + j;
                Asm[srow * 8 + (slot ^ (srow & 7))] = ((uint4*)h)[j];
            }
        }
        {
            const uint4* src = (const uint4*)(BT + (size_t)(colBase + srow) * K + k0 + 32 * shalf);
#pragma unroll
            for (int j = 0; j < 4; j++) {
                int slot = 4 * shalf + j;
                Bsm[srow * 8 + (slot ^ (srow & 7))] = src[j];
            }
        }
        __syncthreads();
#pragma unroll
        for (int ks = 0; ks < 2; ks++) {
            bf16x8 a[4], b[4];
#pragma unroll
            for (int m = 0; m < 4; m++) {
                int row = 64 * wr + 16 * m + r16;
                a[m] = __builtin_bit_cast(bf16x8, Asm[row * 8 + ((4 * ks + g) ^ (row & 7))]);
            }
#pragma unroll
            for (int n = 0; n < 4; n++) {
                int row = 64 * wc + 16 * n + r16;
                b[n] = __builtin_bit_cast(bf16x8, Bsm[row * 8 + ((4 * ks + g) ^ (row & 7))]);
            }
#pragma unroll
            for (int m = 0; m < 4; m++)
#pragma unroll
                for (int n = 0; n < 4; n++)
                    acc[m][n] = __builtin_amdgcn_mfma_f32_16x16x32_bf16(a[m], b[n], acc[m][n], 0, 0, 0);
        }
    }

    // epilogue: D[row = 4g+i (+16m+64wr)][col = r16 (+16n+64wc)]
#pragma unroll
    for (int m = 0; m < 4; m++) {
#pragma unroll
        for (int n = 0; n < 4; n++) {
#pragma unroll
            for (int i = 0; i < 4; i++) {
                int row = rowBase + 64 * wr + 16 * m + 4 * g + i;
                int col = colBase + 64 * wc + 16 * n + r16;
                float v = acc[m][n][i] + bias[col];
                if constexpr (MODE == 3) {
                    ((float*)Out)[(size_t)row * 1024 + col] = v;
                } else {
                    int bidx = row >> 11, s = row & 2047;
                    int hidx = col >> 6, dh = col & 63;
                    if constexpr (MODE == 0) v *= 0.125f;
                    if constexpr (MODE == 2)
                        ((unsigned short*)Out)[(((size_t)(bidx * 16 + hidx)) * 64 + dh) * 2048 + s] = f2bf(v);
                    else
                        ((unsigned short*)Out)[(((size_t)(bidx * 16 + hidx)) * 2048 + s) * 64 + dh] = f2bf(v);
                }
            }
        }
    }
}

// ---------------- flash attention, causal. Block: 64 q-rows (4 waves x 16), k-tiles of 64.
// Swapped QK^T: S^T = K*Q^T so each lane owns one q-row (q = lane&15); softmax in-register.
__global__ __launch_bounds__(256) void attn_kernel(const unsigned short* __restrict__ Q,
                                                   const unsigned short* __restrict__ Kb,
                                                   const unsigned short* __restrict__ VT,
                                                   unsigned short* __restrict__ Xout) {
    __shared__ uint4 Ksm[64 * 8];   // [krow][dh] bf16, XOR-swizzled 16B slots
    __shared__ uint4 Vsm[64 * 8];   // [dh][k]  (V^T tile), same swizzle
    const int t = threadIdx.x;
    const int lane = t & 63, w = t >> 6;
    const int g = lane >> 4, q16 = lane & 15;
    const int qt = blockIdx.x, bh = blockIdx.y;
    const int b = bh >> 4, h = bh & 15;
    const int q0 = qt * 64;
    const int myq = q0 + 16 * w + q16;

    // Q fragments (B-operand of S^T): Q[myq][32ks+8g+j]
    bf16x8 qfrag[2];
    {
        const uint4* qp = (const uint4*)(Q + ((size_t)bh * 2048 + myq) * 64);
        qfrag[0] = __builtin_bit_cast(bf16x8, qp[g]);
        qfrag[1] = __builtin_bit_cast(bf16x8, qp[4 + g]);
    }

    f32x4 acco[4] = {};
    float m = -1e30f, lsum = 0.f;
    const int nkt = qt + 1;
    const int srow = t >> 2, sseg = t & 3;

    for (int kt = 0; kt < nkt; kt++) {
        const int k0 = kt * 64;
        __syncthreads();
        {   // stage K tile [64][64] and V^T tile [64][64]
            const uint4* sk = (const uint4*)(Kb + ((size_t)bh * 2048 + k0 + srow) * 64);
            const uint4* sv = (const uint4*)(VT + ((size_t)bh * 64 + srow) * 2048 + k0);
#pragma unroll
            for (int j = 0; j < 2; j++) {
                int slot = 2 * sseg + j;
                Ksm[srow * 8 + (slot ^ (srow & 7))] = sk[slot];
                Vsm[srow * 8 + (slot ^ (srow & 7))] = sv[slot];
            }
        }
        __syncthreads();

        // S^T: accS[tt] holds D[krow = 16tt+4g+i][q = q16]
        f32x4 accS[4] = {};
#pragma unroll
        for (int ks = 0; ks < 2; ks++) {
#pragma unroll
            for (int tt = 0; tt < 4; tt++) {
                int row = 16 * tt + q16;
                bf16x8 ak = __builtin_bit_cast(bf16x8, Ksm[row * 8 + ((4 * ks + g) ^ (row & 7))]);
                accS[tt] = __builtin_amdgcn_mfma_f32_16x16x32_bf16(ak, qfrag[ks], accS[tt], 0, 0, 0);
            }
        }

        const bool lastTile = (kt == nkt - 1);
        float s[4][4];
#pragma unroll
        for (int tt = 0; tt < 4; tt++)
#pragma unroll
            for (int i = 0; i < 4; i++) {
                float v = accS[tt][i];
                if (lastTile) {
                    int kg = k0 + 16 * tt + 4 * g + i;
                    if (kg > myq) v = -1e30f;
                }
                s[tt][i] = v;
            }

        float pmax = -1e30f;
#pragma unroll
        for (int tt = 0; tt < 4; tt++)
#pragma unroll
            for (int i = 0; i < 4; i++) pmax = fmaxf(pmax, s[tt][i]);
        pmax = fmaxf(pmax, __shfl_xor(pmax, 16));
        pmax = fmaxf(pmax, __shfl_xor(pmax, 32));

        float mnew = fmaxf(m, pmax);
        float sc = __expf(m - mnew);
        m = mnew;

        float tsum = 0.f;
        float p[4][4];
#pragma unroll
        for (int tt = 0; tt < 4; tt++)
#pragma unroll
            for (int i = 0; i < 4; i++) { p[tt][i] = __expf(s[tt][i] - mnew); tsum += p[tt][i]; }
        tsum += __shfl_xor(tsum, 16);
        tsum += __shfl_xor(tsum, 32);
        lsum = lsum * sc + tsum;

        // pack P to bf16 pairs (lane owns k = 16tt+4g..+3 for its q)
        unsigned lo[4], hi[4];
#pragma unroll
        for (int tt = 0; tt < 4; tt++) {
            lo[tt] = (unsigned)f2bf(p[tt][0]) | ((unsigned)f2bf(p[tt][1]) << 16);
            hi[tt] = (unsigned)f2bf(p[tt][2]) | ((unsigned)f2bf(p[tt][3]) << 16);
        }

        // rescale O (O rows are q-local 4g+i; their scale lives at lane 4g+i)
#pragma unroll
        for (int i = 0; i < 4; i++) {
            float sci = __shfl(sc, 4 * g + i);
#pragma unroll
            for (int d = 0; d < 4; d++) acco[d][i] *= sci;
        }

        // PV: A-frag = P[q=q16][k=32ks+8g+j] gathered by shuffle from owner lanes.
        // NOTE: shfl is pull-model — the shuffled VARIABLE's index must be
        // lane-uniform (the value is evaluated at the SOURCE lane). One source
        // lane serves two destinations needing different tt-packs, so we run
        // two shuffle rounds (tt=2ks and tt=2ks+1) and select with OUR gh after.
        const int gh = g >> 1;          // which tt-half this dest needs
        const int g0 = 2 * (g & 1);     // source lane-groups g0, g0+1
        const int srcA = 16 * g0 + q16, srcB = srcA + 16;
#pragma unroll
        for (int ks = 0; ks < 2; ks++) {
            unsigned xa0 = __shfl(lo[2 * ks], srcA);
            unsigned xa1 = __shfl(hi[2 * ks], srcA);
            unsigned xa2 = __shfl(lo[2 * ks], srcB);
            unsigned xa3 = __shfl(hi[2 * ks], srcB);
            unsigned ya0 = __shfl(lo[2 * ks + 1], srcA);
            unsigned ya1 = __shfl(hi[2 * ks + 1], srcA);
            unsigned ya2 = __shfl(lo[2 * ks + 1], srcB);
            unsigned ya3 = __shfl(hi[2 * ks + 1], srcB);
            uint4 pw;
            pw.x = gh ? ya0 : xa0;
            pw.y = gh ? ya1 : xa1;
            pw.z = gh ? ya2 : xa2;
            pw.w = gh ? ya3 : xa3;
            bf16x8 pfrag = __builtin_bit_cast(bf16x8, pw);
#pragma unroll
            for (int d = 0; d < 4; d++) {
                int row = 16 * d + q16;
                bf16x8 bv = __builtin_bit_cast(bf16x8, Vsm[row * 8 + ((4 * ks + g) ^ (row & 7))]);
                acco[d] = __builtin_amdgcn_mfma_f32_16x16x32_bf16(pfrag, bv, acco[d], 0, 0, 0);
            }
        }
    }

    // normalize and write x[B,S,D] bf16: lane holds O[q'=4g+i][dh=16d+q16]
#pragma unroll
    for (int i = 0; i < 4; i++) {
        float li = __shfl(lsum, 4 * g + i);
        float inv = 1.f / li;
        int row = q0 + 16 * w + 4 * g + i;
#pragma unroll
        for (int d = 0; d < 4; d++) {
            int col = h * 64 + 16 * d + q16;
            Xout[((size_t)b * 2048 + row) * 1024 + col] = f2bf(acco[d][i] * inv);
        }
    }
}

extern "C" void kernel_launch(void* const* d_in, const int* in_sizes, int n_in,
                              void* d_out, int out_size, void* d_ws, size_t ws_size,
                              hipStream_t stream) {
    (void)in_sizes; (void)n_in; (void)out_size; (void)ws_size;
    const float* query = (const float*)d_in[0];
    const float* key   = (const float*)d_in[1];
    const float* value = (const float*)d_in[2];
    // d_in[3] = mask (causal tril) — implemented analytically
    const float* Wq = (const float*)d_in[4];
    const float* bq = (const float*)d_in[5];
    const float* Wk = (const float*)d_in[6];
    const float* bk = (const float*)d_in[7];
    const float* Wv = (const float*)d_in[8];
    const float* bv = (const float*)d_in[9];
    const float* Wo = (const float*)d_in[10];
    const float* bo = (const float*)d_in[11];

    char* base = (char*)d_ws;
    const size_t MB = 1u << 20;
    unsigned short* WTq = (unsigned short*)(base + 0 * MB);
    unsigned short* WTk = (unsigned short*)(base + 2 * MB);
    unsigned short* WTv = (unsigned short*)(base + 4 * MB);
    unsigned short* WTo = (unsigned short*)(base + 6 * MB);
    unsigned short* Qb  = (unsigned short*)(base + 8 * MB);
    unsigned short* Kbf = (unsigned short*)(base + 24 * MB);
    unsigned short* VTb = (unsigned short*)(base + 40 * MB);
    unsigned short* Xa  = (unsigned short*)(base + 56 * MB);

    transpose_weights<<<dim3(32, 32, 4), dim3(32, 8), 0, stream>>>(Wq, Wk, Wv, Wo, WTq, WTk, WTv, WTo);
    gemm_bt<false, 0><<<dim3(8, 64), 256, 0, stream>>>(query, WTq, bq, Qb);
    gemm_bt<false, 1><<<dim3(8, 64), 256, 0, stream>>>(key,   WTk, bk, Kbf);
    gemm_bt<false, 2><<<dim3(8, 64), 256, 0, stream>>>(value, WTv, bv, VTb);
    attn_kernel<<<dim3(32, 64), 256, 0, stream>>>(Qb, Kbf, VTb, Xa);
    gemm_bt<true, 3><<<dim3(8, 64), 256, 0, stream>>>(Xa, WTo, bo, (float*)d_out);
}

// Round 3
// 385.160 us; speedup vs baseline: 1.3243x; 1.3243x over previous
//
#include <hip/hip_runtime.h>
#include <hip/hip_bf16.h>

// MHA: B=4, S=2048, D=1024, H=16, DH=64.  All matmuls via mfma_f32_16x16x32_bf16.
// ws layout (MB): WTq@0 WTk@2 WTv@4 WTo@6 | Qb@8 Kb@24 VT@40 | X@56 (shared:
//   cvt scratch for each input GEMM, then Xattn) — total 72MB (same as R1).

typedef __bf16 bf16x8 __attribute__((ext_vector_type(8)));
typedef float f32x4 __attribute__((ext_vector_type(4)));

#define GLOBAL_AS __attribute__((address_space(1)))
#define LDS_AS __attribute__((address_space(3)))

static __device__ __forceinline__ unsigned short f2bf(float f) {
    __bf16 h = (__bf16)f;                       // RNE
    return __builtin_bit_cast(unsigned short, h);
}

static __device__ __forceinline__ void gload_lds16(const void* g, void* l) {
    __builtin_amdgcn_global_load_lds((const GLOBAL_AS void*)g, (LDS_AS void*)l, 16, 0, 0);
}

// ---------------- fp32 -> bf16 bulk convert (8 elems/thread)
__global__ __launch_bounds__(256) void cvt_f32_bf16(const float* __restrict__ src,
                                                    unsigned short* __restrict__ dst, int n8) {
    int i = blockIdx.x * 256 + threadIdx.x;
    if (i >= n8) return;
    const float4* s = (const float4*)src + 2 * (size_t)i;
    float4 v0 = s[0], v1 = s[1];
    unsigned short h[8] = {f2bf(v0.x), f2bf(v0.y), f2bf(v0.z), f2bf(v0.w),
                           f2bf(v1.x), f2bf(v1.y), f2bf(v1.z), f2bf(v1.w)};
    *(uint4*)(dst + 8 * (size_t)i) = *(const uint4*)h;
}

// ---------------- weight transpose: W fp32 [K=1024][N=1024] -> W^T bf16 [N][K]
__global__ void transpose_weights(const float* __restrict__ W0, const float* __restrict__ W1,
                                  const float* __restrict__ W2, const float* __restrict__ W3,
                                  unsigned short* __restrict__ T0, unsigned short* __restrict__ T1,
                                  unsigned short* __restrict__ T2, unsigned short* __restrict__ T3) {
    const float* W; unsigned short* T;
    switch (blockIdx.z) { case 0: W=W0; T=T0; break; case 1: W=W1; T=T1; break;
                          case 2: W=W2; T=T2; break; default: W=W3; T=T3; }
    __shared__ float tile[32][33];
    int tx = threadIdx.x, ty = threadIdx.y;
    int k0 = blockIdx.x * 32, n0 = blockIdx.y * 32;
#pragma unroll
    for (int j = 0; j < 4; j++) tile[ty + 8*j][tx] = W[(size_t)(k0 + ty + 8*j) * 1024 + n0 + tx];
    __syncthreads();
#pragma unroll
    for (int j = 0; j < 4; j++) T[(size_t)(n0 + ty + 8*j) * 1024 + k0 + tx] = f2bf(tile[tx][ty + 8*j]);
}

// ---------------- GEMM (m97 structure): C[8192][1024] = A_bf16 * W + bias, B = W^T bf16 [N][K]
// global_load_lds width-16 staging, linear LDS [128 rows][64 k], 128x128 tile, BK=64.
// MODE 0: out=Q bf16 [B,H,S,DH] scaled 0.125  MODE 1: out=K bf16 [B,H,S,DH]
// MODE 2: out=V^T bf16 [B,H,DH,S]             MODE 3: out=fp32 [M][N] (d_out)
template <int MODE>
__global__ __launch_bounds__(256) void gemm_bt(const unsigned short* __restrict__ A,
                                               const unsigned short* __restrict__ BT,
                                               const float* __restrict__ bias,
                                               void* __restrict__ Out) {
    __shared__ unsigned short Asm[128 * 64];
    __shared__ unsigned short Bsm[128 * 64];
    const int t = threadIdx.x;
    const int lane = t & 63, w = t >> 6;
    const int g = lane >> 4, r16 = lane & 15;
    const int wr = w >> 1, wc = w & 1;
    const int rowBase = blockIdx.y * 128, colBase = blockIdx.x * 128;
    const int K = 1024;
    const int srow = t >> 3;          // 0..31 (+32j)
    const int scol = (t & 7) * 8;     // element offset in row

    // per-thread staging sources (advance by 64 per K-step)
    const unsigned short* srcA[4];
    const unsigned short* srcB[4];
#pragma unroll
    for (int j = 0; j < 4; j++) {
        srcA[j] = A  + (size_t)(rowBase + srow + 32 * j) * K + scol;
        srcB[j] = BT + (size_t)(colBase + srow + 32 * j) * K + scol;
    }
    unsigned short* dstA = Asm + 512 * w;   // + 2048*j, + lane*8 implicit
    unsigned short* dstB = Bsm + 512 * w;

    f32x4 acc[4][4] = {};

    for (int k0 = 0; k0 < K; k0 += 64) {
        __syncthreads();
#pragma unroll
        for (int j = 0; j < 4; j++) {
            gload_lds16(srcA[j] + k0, dstA + 2048 * j);
            gload_lds16(srcB[j] + k0, dstB + 2048 * j);
        }
        __syncthreads();
#pragma unroll
        for (int ks = 0; ks < 2; ks++) {
            bf16x8 a[4], b[4];
#pragma unroll
            for (int m = 0; m < 4; m++) {
                int row = 64 * wr + 16 * m + r16;
                a[m] = *(const bf16x8*)(Asm + row * 64 + 32 * ks + 8 * g);
            }
#pragma unroll
            for (int n = 0; n < 4; n++) {
                int row = 64 * wc + 16 * n + r16;
                b[n] = *(const bf16x8*)(Bsm + row * 64 + 32 * ks + 8 * g);
            }
#pragma unroll
            for (int m = 0; m < 4; m++)
#pragma unroll
                for (int n = 0; n < 4; n++)
                    acc[m][n] = __builtin_amdgcn_mfma_f32_16x16x32_bf16(a[m], b[n], acc[m][n], 0, 0, 0);
        }
    }

    float bv[4];
#pragma unroll
    for (int n = 0; n < 4; n++) bv[n] = bias[colBase + 64 * wc + 16 * n + r16];

    // epilogue: D[row = 4g+i (+16m+64wr)][col = r16 (+16n+64wc)]
#pragma unroll
    for (int m = 0; m < 4; m++) {
#pragma unroll
        for (int n = 0; n < 4; n++) {
#pragma unroll
            for (int i = 0; i < 4; i++) {
                int row = rowBase + 64 * wr + 16 * m + 4 * g + i;
                int col = colBase + 64 * wc + 16 * n + r16;
                float v = acc[m][n][i] + bv[n];
                if constexpr (MODE == 3) {
                    ((float*)Out)[(size_t)row * 1024 + col] = v;
                } else {
                    int bidx = row >> 11, s = row & 2047;
                    int hidx = col >> 6, dh = col & 63;
                    if constexpr (MODE == 0) v *= 0.125f;
                    if constexpr (MODE == 2)
                        ((unsigned short*)Out)[(((size_t)(bidx * 16 + hidx)) * 64 + dh) * 2048 + s] = f2bf(v);
                    else
                        ((unsigned short*)Out)[(((size_t)(bidx * 16 + hidx)) * 2048 + s) * 64 + dh] = f2bf(v);
                }
            }
        }
    }
}

// ---------------- flash attention, causal. Block handles q-tiles (bx, 31-bx): uniform 33 steps.
// K/V double-buffered in LDS via global_load_lds with pre-swizzled source; XOR-swizzled reads.
__global__ __launch_bounds__(256) void attn_kernel(const unsigned short* __restrict__ Q,
                                                   const unsigned short* __restrict__ Kb,
                                                   const unsigned short* __restrict__ VT,
                                                   unsigned short* __restrict__ Xout) {
    __shared__ unsigned short Ksm[2][64 * 64];
    __shared__ unsigned short Vsm[2][64 * 64];
    const int t = threadIdx.x;
    const int lane = t & 63, w = t >> 6;
    const int g = lane >> 4, q16 = lane & 15;
    const int bh = blockIdx.y;
    const int b = bh >> 4, h = bh & 15;

    // staging geometry: load j covers LDS rows t/8 + 32j, slot t&7 (16B);
    // source pre-swizzled so LDS(row,s) = global(row, s^(row&7)).
    const int srow0 = t >> 3;                       // 0..31
    const int ssrc = ((t & 7) ^ (srow0 & 7)) * 8;   // swizzled col (row&7 indep. of j)
    const unsigned short* srcK[2];
    const unsigned short* srcV[2];
#pragma unroll
    for (int j = 0; j < 2; j++) {
        int row = srow0 + 32 * j;
        srcK[j] = Kb + ((size_t)bh * 2048 + row) * 64 + ssrc;    // + 4096*kt
        srcV[j] = VT + ((size_t)bh * 64 + row) * 2048 + ssrc;    // + 64*kt
    }

    const int gh = g >> 1;
    const int g0 = 2 * (g & 1);
    const int srcA = 16 * g0 + q16, srcB = srcA + 16;

#pragma unroll 1
    for (int ph = 0; ph < 2; ph++) {
        const int qt = ph ? (31 - (int)blockIdx.x) : (int)blockIdx.x;
        const int q0 = qt * 64;
        const int myq = q0 + 16 * w + q16;
        const int nkt = qt + 1;

        bf16x8 qfrag[2];
        {
            const uint4* qp = (const uint4*)(Q + ((size_t)bh * 2048 + myq) * 64);
            qfrag[0] = __builtin_bit_cast(bf16x8, qp[g]);
            qfrag[1] = __builtin_bit_cast(bf16x8, qp[4 + g]);
        }

        f32x4 acco[4] = {};
        float m = -1e30f, lsum = 0.f;
        int cur = 0;

        // prologue: stage tile 0 into buffer 0
#pragma unroll
        for (int j = 0; j < 2; j++) {
            gload_lds16(srcK[j], &Ksm[0][512 * w + 2048 * j]);
            gload_lds16(srcV[j], &Vsm[0][512 * w + 2048 * j]);
        }
        __syncthreads();

        for (int kt = 0; kt < nkt; kt++) {
            const int k0 = kt * 64;
            if (kt + 1 < nkt) {   // prefetch next tile into the other buffer
                int nxt = cur ^ 1;
#pragma unroll
                for (int j = 0; j < 2; j++) {
                    gload_lds16(srcK[j] + (size_t)(kt + 1) * 4096, &Ksm[nxt][512 * w + 2048 * j]);
                    gload_lds16(srcV[j] + (size_t)(kt + 1) * 64,   &Vsm[nxt][512 * w + 2048 * j]);
                }
            }

            // S^T: accS[tt] holds D[krow = 16tt+4g+i][q = q16]
            f32x4 accS[4] = {};
#pragma unroll
            for (int ks = 0; ks < 2; ks++) {
#pragma unroll
                for (int tt = 0; tt < 4; tt++) {
                    int row = 16 * tt + q16;
                    bf16x8 ak = *(const bf16x8*)(&Ksm[cur][row * 64 + ((4 * ks + g) ^ (row & 7)) * 8]);
                    accS[tt] = __builtin_amdgcn_mfma_f32_16x16x32_bf16(ak, qfrag[ks], accS[tt], 0, 0, 0);
                }
            }

            const bool lastTile = (kt == nkt - 1);
            float s[4][4];
#pragma unroll
            for (int tt = 0; tt < 4; tt++)
#pragma unroll
                for (int i = 0; i < 4; i++) {
                    float v = accS[tt][i];
                    if (lastTile) {
                        int kg = k0 + 16 * tt + 4 * g + i;
                        if (kg > myq) v = -1e30f;
                    }
                    s[tt][i] = v;
                }

            float pmax = -1e30f;
#pragma unroll
            for (int tt = 0; tt < 4; tt++)
#pragma unroll
                for (int i = 0; i < 4; i++) pmax = fmaxf(pmax, s[tt][i]);
            pmax = fmaxf(pmax, __shfl_xor(pmax, 16));
            pmax = fmaxf(pmax, __shfl_xor(pmax, 32));

            float mnew = fmaxf(m, pmax);
            float sc = __expf(m - mnew);
            m = mnew;

            float tsum = 0.f;
            float p[4][4];
#pragma unroll
            for (int tt = 0; tt < 4; tt++)
#pragma unroll
                for (int i = 0; i < 4; i++) { p[tt][i] = __expf(s[tt][i] - mnew); tsum += p[tt][i]; }
            tsum += __shfl_xor(tsum, 16);
            tsum += __shfl_xor(tsum, 32);
            lsum = lsum * sc + tsum;

            unsigned lo[4], hi[4];
#pragma unroll
            for (int tt = 0; tt < 4; tt++) {
                lo[tt] = (unsigned)f2bf(p[tt][0]) | ((unsigned)f2bf(p[tt][1]) << 16);
                hi[tt] = (unsigned)f2bf(p[tt][2]) | ((unsigned)f2bf(p[tt][3]) << 16);
            }

#pragma unroll
            for (int i = 0; i < 4; i++) {
                float sci = __shfl(sc, 4 * g + i);
#pragma unroll
                for (int d = 0; d < 4; d++) acco[d][i] *= sci;
            }

            // PV: two shuffle rounds (tt=2ks, 2ks+1); dest selects with its own gh after.
#pragma unroll
            for (int ks = 0; ks < 2; ks++) {
                unsigned xa0 = __shfl(lo[2 * ks], srcA);
                unsigned xa1 = __shfl(hi[2 * ks], srcA);
                unsigned xa2 = __shfl(lo[2 * ks], srcB);
                unsigned xa3 = __shfl(hi[2 * ks], srcB);
                unsigned ya0 = __shfl(lo[2 * ks + 1], srcA);
                unsigned ya1 = __shfl(hi[2 * ks + 1], srcA);
                unsigned ya2 = __shfl(lo[2 * ks + 1], srcB);
                unsigned ya3 = __shfl(hi[2 * ks + 1], srcB);
                uint4 pw;
                pw.x = gh ? ya0 : xa0;
                pw.y = gh ? ya1 : xa1;
                pw.z = gh ? ya2 : xa2;
                pw.w = gh ? ya3 : xa3;
                bf16x8 pfrag = __builtin_bit_cast(bf16x8, pw);
#pragma unroll
                for (int d = 0; d < 4; d++) {
                    int row = 16 * d + q16;
                    bf16x8 vv = *(const bf16x8*)(&Vsm[cur][row * 64 + ((4 * ks + g) ^ (row & 7)) * 8]);
                    acco[d] = __builtin_amdgcn_mfma_f32_16x16x32_bf16(pfrag, vv, acco[d], 0, 0, 0);
                }
            }

            __syncthreads();   // drains prefetch vmcnt + protects buffer swap
            cur ^= 1;
        }

        // normalize and write x[B,S,D] bf16: lane holds O[q'=4g+i][dh=16d+q16]
#pragma unroll
        for (int i = 0; i < 4; i++) {
            float li = __shfl(lsum, 4 * g + i);
            float inv = 1.f / li;
            int row = q0 + 16 * w + 4 * g + i;
#pragma unroll
            for (int d = 0; d < 4; d++) {
                int col = h * 64 + 16 * d + q16;
                Xout[((size_t)b * 2048 + row) * 1024 + col] = f2bf(acco[d][i] * inv);
            }
        }
        __syncthreads();   // phase boundary: buffers reused from scratch
    }
}

extern "C" void kernel_launch(void* const* d_in, const int* in_sizes, int n_in,
                              void* d_out, int out_size, void* d_ws, size_t ws_size,
                              hipStream_t stream) {
    (void)in_sizes; (void)n_in; (void)out_size; (void)ws_size;
    const float* query = (const float*)d_in[0];
    const float* key   = (const float*)d_in[1];
    const float* value = (const float*)d_in[2];
    // d_in[3] = mask (causal tril) — implemented analytically
    const float* Wq = (const float*)d_in[4];
    const float* bq = (const float*)d_in[5];
    const float* Wk = (const float*)d_in[6];
    const float* bk = (const float*)d_in[7];
    const float* Wv = (const float*)d_in[8];
    const float* bv = (const float*)d_in[9];
    const float* Wo = (const float*)d_in[10];
    const float* bo = (const float*)d_in[11];

    char* base = (char*)d_ws;
    const size_t MB = 1u << 20;
    unsigned short* WTq = (unsigned short*)(base + 0 * MB);
    unsigned short* WTk = (unsigned short*)(base + 2 * MB);
    unsigned short* WTv = (unsigned short*)(base + 4 * MB);
    unsigned short* WTo = (unsigned short*)(base + 6 * MB);
    unsigned short* Qb  = (unsigned short*)(base + 8 * MB);
    unsigned short* Kbf = (unsigned short*)(base + 24 * MB);
    unsigned short* VTb = (unsigned short*)(base + 40 * MB);
    unsigned short* X   = (unsigned short*)(base + 56 * MB);  // cvt scratch, then Xattn

    const int n8 = (8192 * 1024) / 8;

    transpose_weights<<<dim3(32, 32, 4), dim3(32, 8), 0, stream>>>(Wq, Wk, Wv, Wo, WTq, WTk, WTv, WTo);

    cvt_f32_bf16<<<4096, 256, 0, stream>>>(query, X, n8);
    gemm_bt<0><<<dim3(8, 64), 256, 0, stream>>>(X, WTq, bq, Qb);
    cvt_f32_bf16<<<4096, 256, 0, stream>>>(key, X, n8);
    gemm_bt<1><<<dim3(8, 64), 256, 0, stream>>>(X, WTk, bk, Kbf);
    cvt_f32_bf16<<<4096, 256, 0, stream>>>(value, X, n8);
    gemm_bt<2><<<dim3(8, 64), 256, 0, stream>>>(X, WTv, bv, VTb);

    attn_kernel<<<dim3(16, 64), 256, 0, stream>>>(Qb, Kbf, VTb, X);
    gemm_bt<3><<<dim3(8, 64), 256, 0, stream>>>(X, WTo, bo, (float*)d_out);
}